// Round 7
// baseline (729.814 us; speedup 1.0000x reference)
//
#include <hip/hip_runtime.h>
#include <cstdint>

#define S_ELEMS 2097152ull   // B*T*N = 16*2048*64
#define TT 2048
#define NN 64

__device__ __forceinline__ float gelu_f(float x) {
  float x2 = x * x;
  float z = -1.5957691216057308f * x * (1.0f + 0.044715f * x2);
  return __fdividef(x, 1.0f + __expf(z));
}

__device__ __forceinline__ float2 cmul(float2 a, float2 b) {
  return make_float2(a.x * b.x - a.y * b.y, a.x * b.y + a.y * b.x);
}

// ---------------------------------------------------------------------------
// Kernel 1: warm_start_fill. 256 blocks x 256 thr. (unchanged)
// ---------------------------------------------------------------------------
__global__ __launch_bounds__(256) void fill_kernel(
    const float* __restrict__ x, const float* __restrict__ mask,
    float* __restrict__ seed_out, float* __restrict__ xsT)
{
  __shared__ float s_last[64][4], s_vfirst[64][4];
  __shared__ int   s_has[64][4], s_fidx[64][4];
  __shared__ float s_cl[64][4], s_bv[64][4];
  __shared__ int   s_ch[64][4], s_bh[64][4];
  __shared__ int   s_fg[4];

  const int tid = threadIdx.x;
  const int s4 = tid & 3, c = tid >> 2;
  const int b = blockIdx.x >> 4;
  const int n = ((blockIdx.x & 15) << 2) + s4;
  const size_t base = (size_t)b * (TT * NN) + n;
  const int t0 = c << 5;

  float ff[32];
  float last = 0.f; int has = 0; int fidx = TT; float vfirst = 0.f;
  #pragma unroll
  for (int i = 0; i < 32; ++i) {
    size_t off = base + (size_t)(t0 + i) * NN;
    float v = x[off];
    float m = mask[off];
    bool obs = (m == 0.0f);
    if (obs) { last = v; if (!has) { has = 1; fidx = t0 + i; vfirst = v; } }
    ff[i] = obs ? v : last;
  }
  s_last[c][s4] = last; s_has[c][s4] = has;
  s_vfirst[c][s4] = vfirst; s_fidx[c][s4] = fidx;
  __syncthreads();

  if (tid < 4) {
    float cl = 0.f; int ch = 0; int fg = TT;
    for (int cc = 0; cc < 64; ++cc) {
      s_cl[cc][tid] = cl; s_ch[cc][tid] = ch;
      if (s_has[cc][tid]) {
        cl = s_last[cc][tid]; ch = 1;
        if (fg == TT) fg = s_fidx[cc][tid];
      }
    }
    s_fg[tid] = fg;
    float bv = 0.f; int bh = 0;
    for (int cc = 63; cc >= 0; --cc) {
      s_bv[cc][tid] = bv; s_bh[cc][tid] = bh;
      if (s_has[cc][tid]) { bv = s_vfirst[cc][tid]; bh = 1; }
    }
  }
  __syncthreads();

  const float cl  = s_cl[c][s4]; const int ch  = s_ch[c][s4];
  const float bcv = s_bv[c][s4]; const int bch = s_bh[c][s4];
  const int firstg = s_fg[s4];
  const float pre = ch ? cl : 0.f;
  const int floc = fidx - t0;
  const size_t tbase = ((size_t)b * NN + n) * TT;

  float lastb = 0.f; int hasb = 0;
  float xb0, xb1, xb2, xb3;
  #pragma unroll
  for (int i = 31; i >= 0; --i) {
    int t = t0 + i;
    size_t off = base + (size_t)t * NN;
    float v = x[off];
    float m = mask[off];
    bool obs = (m == 0.0f);
    if (obs) { lastb = v; hasb = 1; }
    float bf = hasb ? lastb : bcv;
    int bav = hasb | bch;
    float ffv = (i < floc) ? pre : ff[i];
    int fav = (t >= firstg) ? 1 : 0;
    float sv;
    if (obs) sv = v;
    else if (fav && bav) sv = 0.5f * (ffv + bf);
    else if (fav) sv = ffv;
    else if (bav) sv = bf;
    else sv = 0.f;
    seed_out[off] = sv;
    if ((i & 3) == 3) xb3 = sv;
    else if ((i & 3) == 2) xb2 = sv;
    else if ((i & 3) == 1) xb1 = sv;
    else {
      xb0 = sv;
      *(float4*)(xsT + tbase + t) = make_float4(xb0, xb1, xb2, xb3);
    }
  }
}

// ---------------------------------------------------------------------------
// Kernel 2: adjacency + filter transpose. (unchanged)
// ---------------------------------------------------------------------------
__global__ __launch_bounds__(256) void adj_prep_kernel(
    const float* __restrict__ node_emb,
    const float* __restrict__ fre, const float* __restrict__ fim,
    float* __restrict__ adj, float2* __restrict__ filtT)
{
  const int tid = threadIdx.x;
  if (blockIdx.x == 0) {
    __shared__ float E[64 * 32];
    for (int i = tid; i < 2048; i += 256) E[i] = node_emb[i];
    __syncthreads();
    if (tid < 64) {
      float er[32];
      #pragma unroll
      for (int k = 0; k < 32; ++k) er[k] = E[tid * 32 + k];
      float sc[64];
      float mx = -1e30f;
      #pragma unroll
      for (int j = 0; j < 64; ++j) {
        float acc = 0.f;
        #pragma unroll
        for (int k = 0; k < 32; ++k) acc += er[k] * E[j * 32 + k];
        acc = fmaxf(acc, 0.f);
        sc[j] = acc;
        mx = fmaxf(mx, acc);
      }
      float sum = 0.f;
      #pragma unroll
      for (int j = 0; j < 64; ++j) { float e = __expf(sc[j] - mx); sc[j] = e; sum += e; }
      float inv = __fdividef(1.f, sum);
      #pragma unroll
      for (int j = 0; j < 64; ++j) adj[tid * 64 + j] = sc[j] * inv;
    }
  } else {
    for (int idx = (blockIdx.x - 1) * 256 + tid; idx < 1025 * 64; idx += 5 * 256) {
      int k = idx >> 6, nn = idx & 63;
      filtT[(size_t)nn * 1025 + k] = make_float2(fre[idx], fim[idx]);
    }
  }
}

// ---------------------------------------------------------------------------
// Kernel 3: x_gcn, 32 rows/block. (unchanged)
// ---------------------------------------------------------------------------
__global__ __launch_bounds__(256) void gcn_kernel(
    const float* __restrict__ seed, const float* __restrict__ adj,
    const float* __restrict__ w1, const float* __restrict__ b1,
    const float* __restrict__ w2, const float* __restrict__ b2p,
    float* __restrict__ xgcn)
{
  __shared__ float At[64 * 65];
  __shared__ float su[4][64];
  __shared__ float sw1[32], sb1[32], sw2[32];
  const int tid = threadIdx.x;
  for (int i = tid; i < 4096; i += 256) {
    int nn = i >> 6, m = i & 63;
    At[m * 65 + nn] = adj[i];
  }
  if (tid < 32) { sw1[tid] = w1[tid]; sb1[tid] = b1[tid]; sw2[tid] = w2[tid]; }
  const float b2 = b2p[0];
  const int r = tid >> 6, n = tid & 63;
  const size_t row0 = (size_t)blockIdx.x * 32;

  for (int it = 0; it < 8; ++it) {
    __syncthreads();
    size_t row = row0 + it * 4 + r;
    float xv = seed[row * 64 + n];
    float u = 0.f;
    #pragma unroll
    for (int h = 0; h < 32; ++h) u += sw2[h] * gelu_f(xv * sw1[h] + sb1[h]);
    su[r][n] = u;
    __syncthreads();
    float acc = b2;
    #pragma unroll 16
    for (int m = 0; m < 64; ++m) acc += At[m * 65 + n] * su[r][m];
    xgcn[row * 64 + n] = acc;
  }
}

// ---------------------------------------------------------------------------
// Kernel 4: FFT filter, radix-4. (unchanged)
// ---------------------------------------------------------------------------
__global__ __launch_bounds__(256) void fft_kernel(
    const float* __restrict__ xsT, const float2* __restrict__ filtT,
    float* __restrict__ xfreq)
{
  __shared__ float2 D[2048];
  __shared__ float2 TW[1024];
  __shared__ float2 FL[1025];
  const int tid = threadIdx.x;
  const int series = blockIdx.x;
  const int bb = series >> 6, n = series & 63;

  for (int m = tid; m < 1024; m += 256) {
    float s, c;
    __sincosf(-3.0679615757712823e-3f * (float)m, &s, &c);  // -2*pi*m/2048
    TW[m] = make_float2(c, s);
  }
  {
    const float2* fsrc = filtT + (size_t)n * 1025;
    for (int i = tid; i < 1025; i += 256) FL[i] = fsrc[i];
  }
  const float* src = xsT + (size_t)series * TT;
  for (int i = tid; i < TT; i += 256) D[i] = make_float2(src[i], 0.f);
  __syncthreads();

  #pragma unroll
  for (int lh = 9; lh >= 1; lh -= 2) {
    const int h = 1 << lh;
    const int tstr = 512 >> lh;
    #pragma unroll
    for (int w = 0; w < 2; ++w) {
      const int u = tid + (w << 8);
      const int j = u & (h - 1);
      const int p = ((u >> lh) << (lh + 2)) + j;
      float2 x0 = D[p], x1 = D[p + h], x2 = D[p + 2 * h], x3 = D[p + 3 * h];
      float2 W  = TW[j * tstr];
      float2 W2 = TW[2 * j * tstr];
      float2 W3 = cmul(W, W2);
      float2 s02 = make_float2(x0.x + x2.x, x0.y + x2.y);
      float2 d02 = make_float2(x0.x - x2.x, x0.y - x2.y);
      float2 s13 = make_float2(x1.x + x3.x, x1.y + x3.y);
      float2 d13 = make_float2(x1.x - x3.x, x1.y - x3.y);
      D[p]         = make_float2(s02.x + s13.x, s02.y + s13.y);
      D[p + h]     = cmul(make_float2(s02.x - s13.x, s02.y - s13.y), W2);
      D[p + 2 * h] = cmul(make_float2(d02.x + d13.y, d02.y - d13.x), W);
      D[p + 3 * h] = cmul(make_float2(d02.x - d13.y, d02.y + d13.x), W3);
    }
    __syncthreads();
  }
  #pragma unroll
  for (int w = 0; w < 4; ++w) {
    const int u = tid + (w << 8);
    const int p = u * 2;
    float2 a = D[p], b = D[p + 1];
    D[p]     = make_float2(a.x + b.x, a.y + b.y);
    D[p + 1] = make_float2(a.x - b.x, a.y - b.y);
  }
  __syncthreads();

  for (int p = tid; p < TT; p += 256) {
    const int k = (int)(__brev((unsigned)p) >> 21);
    float2 f;
    if (k <= 1024) f = FL[k];
    else { f = FL[2048 - k]; f.y = -f.y; }
    float2 Xv = D[p];
    float pr = Xv.x * f.x - Xv.y * f.y;
    float pi = Xv.x * f.y + Xv.y * f.x;
    if (k == 0 || k == 1024) pi = 0.f;
    D[p] = make_float2(pr, pi);
  }
  __syncthreads();

  #pragma unroll
  for (int w = 0; w < 4; ++w) {
    const int u = tid + (w << 8);
    const int p = u * 2;
    float2 a = D[p], b = D[p + 1];
    D[p]     = make_float2(a.x + b.x, a.y + b.y);
    D[p + 1] = make_float2(a.x - b.x, a.y - b.y);
  }
  __syncthreads();
  #pragma unroll
  for (int lh = 1; lh <= 9; lh += 2) {
    const int h = 1 << lh;
    const int tstr = 512 >> lh;
    #pragma unroll
    for (int w = 0; w < 2; ++w) {
      const int u = tid + (w << 8);
      const int j = u & (h - 1);
      const int p = ((u >> lh) << (lh + 2)) + j;
      float2 z0 = D[p], z1 = D[p + h], z2 = D[p + 2 * h], z3 = D[p + 3 * h];
      float2 W  = TW[j * tstr];
      float2 W2 = TW[2 * j * tstr];
      float2 cW  = make_float2(W.x, -W.y);
      float2 cW2 = make_float2(W2.x, -W2.y);
      float2 icW = make_float2(-cW.y, cW.x);
      float2 t1 = cmul(z1, cW2);
      float2 y0 = make_float2(z0.x + t1.x, z0.y + t1.y);
      float2 y1 = make_float2(z0.x - t1.x, z0.y - t1.y);
      float2 t3 = cmul(z3, cW2);
      float2 y2 = make_float2(z2.x + t3.x, z2.y + t3.y);
      float2 y3 = make_float2(z2.x - t3.x, z2.y - t3.y);
      float2 u2 = cmul(y2, cW);
      float2 u3 = cmul(y3, icW);
      D[p]         = make_float2(y0.x + u2.x, y0.y + u2.y);
      D[p + 2 * h] = make_float2(y0.x - u2.x, y0.y - u2.y);
      D[p + h]     = make_float2(y1.x + u3.x, y1.y + u3.y);
      D[p + 3 * h] = make_float2(y1.x - u3.x, y1.y - u3.y);
    }
    __syncthreads();
  }

  const float inv = (1.0f / 2048.0f);
  const size_t obase = (size_t)bb * (TT * NN) + n;
  for (int t2 = tid; t2 < TT; t2 += 256) {
    xfreq[obase + (size_t)t2 * NN] = D[t2].x * inv;
  }
}

// ---------------------------------------------------------------------------
// Kernel 5: gate MLP, RESTRUCTURED: 4 threads per element (quad = 4
// consecutive lanes). Thread q owns acts k in [16q,16q+16) and output
// channels h in [16q,16q+16): 16 act + 16 acc regs, bounded by construction
// (rounds 4-6: 1-thread/elem version spilled its 64-float accumulator under
// any codegen mood; hints did not help). Act exchange = 3x16 shfl_xor within
// the quad; L3 = per-thread partial + 2-step quad shfl reduce.
// Grid: 32768 blocks x 256 thr = 64 elements/block.
// ---------------------------------------------------------------------------
__global__ __launch_bounds__(256) void mlp_kernel(
    const float* __restrict__ xin, const float* __restrict__ mask, const int* __restrict__ rate_id,
    const float* __restrict__ rate_table,
    const float* __restrict__ gw1, const float* __restrict__ gb1,
    const float* __restrict__ gw2, const float* __restrict__ gb2,
    const float* __restrict__ gw3, const float* __restrict__ gb3,
    float* __restrict__ out)
{
  __shared__ __align__(16) float s_gw2[4096];   // [k][h] row-major
  __shared__ __align__(16) float s_l1[512];     // [k][8]: slots 0..5 = gw1[c][k]
  __shared__ __align__(16) float s_b1rT[512];   // [k][8]: per-rate L1 bias
  __shared__ float s_w3d[64], s_gb2[64];
  __shared__ float s_seed[64], s_gcn[64], s_freq[64], s_mask[64], s_xin[64];
  __shared__ int s_rid[64];
  const int tid = threadIdx.x;

  for (int i = tid; i < 4096; i += 256) s_gw2[i] = gw2[i];
  for (int i = tid; i < 512; i += 256) {
    int k = i >> 3, c = i & 7;
    s_l1[i] = (c < 6) ? gw1[c * 64 + k] : 0.f;
  }
  for (int i = tid; i < 512; i += 256) {
    int k = i >> 3, r = i & 7;
    float acc = gb1[k];
    #pragma unroll
    for (int e = 0; e < 16; ++e) acc += rate_table[r * 16 + e] * gw1[(6 + e) * 64 + k];
    s_b1rT[i] = acc;
  }
  if (tid < 64) {
    s_w3d[tid] = gw3[tid * 2] - gw3[tid * 2 + 1];
    s_gb2[tid] = gb2[tid];
    s_rid[tid] = rate_id[tid];
  }
  {
    const int a = tid >> 6, e = tid & 63;
    const size_t gidx = (size_t)blockIdx.x * 64 + e;
    if (a == 0) { s_seed[e] = out[gidx]; s_xin[e] = xin[gidx]; }
    else if (a == 1) s_gcn[e]  = out[S_ELEMS + gidx];
    else if (a == 2) s_freq[e] = out[2 * S_ELEMS + gidx];
    else             s_mask[e] = mask[gidx];
  }
  __syncthreads();

  const int q = tid & 3;           // quad member: act/channel chunk owner
  const int e = tid >> 2;          // element within block
  const size_t idx = (size_t)blockIdx.x * 64 + e;

  const float f0 = s_seed[e], f1 = s_mask[e], f2 = s_gcn[e], f3 = s_freq[e];
  const float f4 = f2 - f0, f5 = f3 - f0;
  const int rid = s_rid[e];        // idx % 64 == e (block base is x64)

  // L1: 16 activations for k in [16q, 16q+16)
  const float4* l1v = (const float4*)s_l1;
  float act[16];
  #pragma unroll
  for (int i = 0; i < 16; ++i) {
    const int k = (q << 4) + i;
    float4 wA = l1v[k * 2], wB = l1v[k * 2 + 1];
    float a = s_b1rT[k * 8 + rid]
            + wA.x * f0 + wA.y * f1 + wA.z * f2 + wA.w * f3 + wB.x * f4 + wB.y * f5;
    act[i] = gelu_f(a);
  }

  // L2: acc over h in [16q, 16q+16); acts gathered from quad via shfl_xor
  float acc[16];
  #pragma unroll
  for (int i = 0; i < 16; ++i) acc[i] = s_gb2[(q << 4) + i];
  const float4* w2v = (const float4*)s_gw2;
  #pragma unroll
  for (int r = 0; r < 4; ++r) {
    const int kbase = ((q ^ r) << 4);
    #pragma unroll
    for (int i = 0; i < 16; ++i) {
      float av = (r == 0) ? act[i] : __shfl_xor(act[i], r, 64);
      const float4* wrow = w2v + (kbase + i) * 16 + (q << 2);
      float4 wa = wrow[0], wb = wrow[1], wc = wrow[2], wd = wrow[3];
      acc[0]  += av * wa.x; acc[1]  += av * wa.y; acc[2]  += av * wa.z; acc[3]  += av * wa.w;
      acc[4]  += av * wb.x; acc[5]  += av * wb.y; acc[6]  += av * wb.z; acc[7]  += av * wb.w;
      acc[8]  += av * wc.x; acc[9]  += av * wc.y; acc[10] += av * wc.z; acc[11] += av * wc.w;
      acc[12] += av * wd.x; acc[13] += av * wd.y; acc[14] += av * wd.z; acc[15] += av * wd.w;
    }
  }

  // L3: partial logit-diff, then quad reduce
  float d = 0.f;
  #pragma unroll
  for (int i = 0; i < 16; ++i) d += gelu_f(acc[i]) * s_w3d[(q << 4) + i];
  d += __shfl_xor(d, 1, 64);
  d += __shfl_xor(d, 2, 64);
  d += gb3[0] - gb3[1];

  const float w0 = __fdividef(1.0f, 1.0f + __expf(-d));
  const float w1g = 1.0f - w0;
  const float ximp = w0 * f2 + w1g * f3;
  if (q == 0)      out[3 * S_ELEMS + idx] = ximp;
  else if (q == 1) out[4 * S_ELEMS + idx] = (f1 != 0.0f) ? ximp : s_xin[e];
  else if (q == 2) ((float2*)(out + 5 * S_ELEMS))[idx] = make_float2(w0, w1g);
}

// ---------------------------------------------------------------------------
extern "C" void kernel_launch(void* const* d_in, const int* in_sizes, int n_in,
                              void* d_out, int out_size, void* d_ws, size_t ws_size,
                              hipStream_t stream) {
  (void)in_sizes; (void)n_in; (void)out_size; (void)d_ws; (void)ws_size;
  const float* x_input    = (const float*)d_in[0];
  const float* mask       = (const float*)d_in[1];
  const int*   rate_id    = (const int*)d_in[2];
  const float* node_emb   = (const float*)d_in[3];
  const float* gcn_w1     = (const float*)d_in[4];
  const float* gcn_b1     = (const float*)d_in[5];
  const float* gcn_w2     = (const float*)d_in[6];
  const float* gcn_b2     = (const float*)d_in[7];
  const float* freq_re    = (const float*)d_in[8];
  const float* freq_im    = (const float*)d_in[9];
  const float* rate_table = (const float*)d_in[10];
  const float* gw1        = (const float*)d_in[11];
  const float* gb1        = (const float*)d_in[12];
  const float* gw2        = (const float*)d_in[13];
  const float* gb2        = (const float*)d_in[14];
  const float* gw3        = (const float*)d_in[15];
  const float* gb3        = (const float*)d_in[16];
  float* out = (float*)d_out;

  float* out0 = out;                 // x_seed
  float* out1 = out + S_ELEMS;       // x_gcn
  float* out2 = out + 2 * S_ELEMS;   // x_freq
  float* out4 = out + 4 * S_ELEMS;   // scratch (seed^T) -> x_complete (mlp)
  float* out6 = out + 7 * S_ELEMS;   // adjacency
  float2* filtT = (float2*)(out + 5 * S_ELEMS);  // scratch -> gate weights (mlp)

  fill_kernel<<<256, 256, 0, stream>>>(x_input, mask, out0, out4);
  adj_prep_kernel<<<6, 256, 0, stream>>>(node_emb, freq_re, freq_im, out6, filtT);
  gcn_kernel<<<1024, 256, 0, stream>>>(out0, out6, gcn_w1, gcn_b1, gcn_w2, gcn_b2, out1);
  fft_kernel<<<1024, 256, 0, stream>>>(out4, filtT, out2);
  mlp_kernel<<<32768, 256, 0, stream>>>(x_input, mask, rate_id, rate_table,
                                        gw1, gb1, gw2, gb2, gw3, gb3, out);
}

// Round 9
// 500.631 us; speedup vs baseline: 1.4578x; 1.4578x over previous
//
#include <hip/hip_runtime.h>
#include <cstdint>

#define S_ELEMS 2097152ull   // B*T*N = 16*2048*64
#define TT 2048
#define NN 64

typedef __attribute__((ext_vector_type(8))) short bf16x8;
typedef __attribute__((ext_vector_type(4))) float f32x4;

__device__ __forceinline__ float gelu_f(float x) {
  float x2 = x * x;
  float z = -1.5957691216057308f * x * (1.0f + 0.044715f * x2);
  return __fdividef(x, 1.0f + __expf(z));
}

__device__ __forceinline__ float2 cmul(float2 a, float2 b) {
  return make_float2(a.x * b.x - a.y * b.y, a.x * b.y + a.y * b.x);
}

__device__ __forceinline__ uint16_t f2bf(float x) {   // RNE float->bf16 bits
  uint32_t u = __float_as_uint(x);
  return (uint16_t)((u + 0x7FFFu + ((u >> 16) & 1u)) >> 16);
}

// ---------------------------------------------------------------------------
// Kernel 1: warm_start_fill. (unchanged)
// ---------------------------------------------------------------------------
__global__ __launch_bounds__(256) void fill_kernel(
    const float* __restrict__ x, const float* __restrict__ mask,
    float* __restrict__ seed_out, float* __restrict__ xsT)
{
  __shared__ float s_last[64][4], s_vfirst[64][4];
  __shared__ int   s_has[64][4], s_fidx[64][4];
  __shared__ float s_cl[64][4], s_bv[64][4];
  __shared__ int   s_ch[64][4], s_bh[64][4];
  __shared__ int   s_fg[4];

  const int tid = threadIdx.x;
  const int s4 = tid & 3, c = tid >> 2;
  const int b = blockIdx.x >> 4;
  const int n = ((blockIdx.x & 15) << 2) + s4;
  const size_t base = (size_t)b * (TT * NN) + n;
  const int t0 = c << 5;

  float ff[32];
  float last = 0.f; int has = 0; int fidx = TT; float vfirst = 0.f;
  #pragma unroll
  for (int i = 0; i < 32; ++i) {
    size_t off = base + (size_t)(t0 + i) * NN;
    float v = x[off];
    float m = mask[off];
    bool obs = (m == 0.0f);
    if (obs) { last = v; if (!has) { has = 1; fidx = t0 + i; vfirst = v; } }
    ff[i] = obs ? v : last;
  }
  s_last[c][s4] = last; s_has[c][s4] = has;
  s_vfirst[c][s4] = vfirst; s_fidx[c][s4] = fidx;
  __syncthreads();

  if (tid < 4) {
    float cl = 0.f; int ch = 0; int fg = TT;
    for (int cc = 0; cc < 64; ++cc) {
      s_cl[cc][tid] = cl; s_ch[cc][tid] = ch;
      if (s_has[cc][tid]) {
        cl = s_last[cc][tid]; ch = 1;
        if (fg == TT) fg = s_fidx[cc][tid];
      }
    }
    s_fg[tid] = fg;
    float bv = 0.f; int bh = 0;
    for (int cc = 63; cc >= 0; --cc) {
      s_bv[cc][tid] = bv; s_bh[cc][tid] = bh;
      if (s_has[cc][tid]) { bv = s_vfirst[cc][tid]; bh = 1; }
    }
  }
  __syncthreads();

  const float cl  = s_cl[c][s4]; const int ch  = s_ch[c][s4];
  const float bcv = s_bv[c][s4]; const int bch = s_bh[c][s4];
  const int firstg = s_fg[s4];
  const float pre = ch ? cl : 0.f;
  const int floc = fidx - t0;
  const size_t tbase = ((size_t)b * NN + n) * TT;

  float lastb = 0.f; int hasb = 0;
  float xb0, xb1, xb2, xb3;
  #pragma unroll
  for (int i = 31; i >= 0; --i) {
    int t = t0 + i;
    size_t off = base + (size_t)t * NN;
    float v = x[off];
    float m = mask[off];
    bool obs = (m == 0.0f);
    if (obs) { lastb = v; hasb = 1; }
    float bf = hasb ? lastb : bcv;
    int bav = hasb | bch;
    float ffv = (i < floc) ? pre : ff[i];
    int fav = (t >= firstg) ? 1 : 0;
    float sv;
    if (obs) sv = v;
    else if (fav && bav) sv = 0.5f * (ffv + bf);
    else if (fav) sv = ffv;
    else if (bav) sv = bf;
    else sv = 0.f;
    seed_out[off] = sv;
    if ((i & 3) == 3) xb3 = sv;
    else if ((i & 3) == 2) xb2 = sv;
    else if ((i & 3) == 1) xb1 = sv;
    else {
      xb0 = sv;
      *(float4*)(xsT + tbase + t) = make_float4(xb0, xb1, xb2, xb3);
    }
  }
}

// ---------------------------------------------------------------------------
// Kernel 2: adjacency + filter transpose. (unchanged)
// ---------------------------------------------------------------------------
__global__ __launch_bounds__(256) void adj_prep_kernel(
    const float* __restrict__ node_emb,
    const float* __restrict__ fre, const float* __restrict__ fim,
    float* __restrict__ adj, float2* __restrict__ filtT)
{
  const int tid = threadIdx.x;
  if (blockIdx.x == 0) {
    __shared__ float E[64 * 32];
    for (int i = tid; i < 2048; i += 256) E[i] = node_emb[i];
    __syncthreads();
    if (tid < 64) {
      float er[32];
      #pragma unroll
      for (int k = 0; k < 32; ++k) er[k] = E[tid * 32 + k];
      float sc[64];
      float mx = -1e30f;
      #pragma unroll
      for (int j = 0; j < 64; ++j) {
        float acc = 0.f;
        #pragma unroll
        for (int k = 0; k < 32; ++k) acc += er[k] * E[j * 32 + k];
        acc = fmaxf(acc, 0.f);
        sc[j] = acc;
        mx = fmaxf(mx, acc);
      }
      float sum = 0.f;
      #pragma unroll
      for (int j = 0; j < 64; ++j) { float e = __expf(sc[j] - mx); sc[j] = e; sum += e; }
      float inv = __fdividef(1.f, sum);
      #pragma unroll
      for (int j = 0; j < 64; ++j) adj[tid * 64 + j] = sc[j] * inv;
    }
  } else {
    for (int idx = (blockIdx.x - 1) * 256 + tid; idx < 1025 * 64; idx += 5 * 256) {
      int k = idx >> 6, nn = idx & 63;
      filtT[(size_t)nn * 1025 + k] = make_float2(fre[idx], fim[idx]);
    }
  }
}

// ---------------------------------------------------------------------------
// Kernel 3: x_gcn, 32 rows/block. (unchanged)
// ---------------------------------------------------------------------------
__global__ __launch_bounds__(256) void gcn_kernel(
    const float* __restrict__ seed, const float* __restrict__ adj,
    const float* __restrict__ w1, const float* __restrict__ b1,
    const float* __restrict__ w2, const float* __restrict__ b2p,
    float* __restrict__ xgcn)
{
  __shared__ float At[64 * 65];
  __shared__ float su[4][64];
  __shared__ float sw1[32], sb1[32], sw2[32];
  const int tid = threadIdx.x;
  for (int i = tid; i < 4096; i += 256) {
    int nn = i >> 6, m = i & 63;
    At[m * 65 + nn] = adj[i];
  }
  if (tid < 32) { sw1[tid] = w1[tid]; sb1[tid] = b1[tid]; sw2[tid] = w2[tid]; }
  const float b2 = b2p[0];
  const int r = tid >> 6, n = tid & 63;
  const size_t row0 = (size_t)blockIdx.x * 32;

  for (int it = 0; it < 8; ++it) {
    __syncthreads();
    size_t row = row0 + it * 4 + r;
    float xv = seed[row * 64 + n];
    float u = 0.f;
    #pragma unroll
    for (int h = 0; h < 32; ++h) u += sw2[h] * gelu_f(xv * sw1[h] + sb1[h]);
    su[r][n] = u;
    __syncthreads();
    float acc = b2;
    #pragma unroll 16
    for (int m = 0; m < 64; ++m) acc += At[m * 65 + n] * su[r][m];
    xgcn[row * 64 + n] = acc;
  }
}

// ---------------------------------------------------------------------------
// Kernel 4: FFT filter, radix-4. (unchanged)
// ---------------------------------------------------------------------------
__global__ __launch_bounds__(256) void fft_kernel(
    const float* __restrict__ xsT, const float2* __restrict__ filtT,
    float* __restrict__ xfreq)
{
  __shared__ float2 D[2048];
  __shared__ float2 TW[1024];
  __shared__ float2 FL[1025];
  const int tid = threadIdx.x;
  const int series = blockIdx.x;
  const int bb = series >> 6, n = series & 63;

  for (int m = tid; m < 1024; m += 256) {
    float s, c;
    __sincosf(-3.0679615757712823e-3f * (float)m, &s, &c);  // -2*pi*m/2048
    TW[m] = make_float2(c, s);
  }
  {
    const float2* fsrc = filtT + (size_t)n * 1025;
    for (int i = tid; i < 1025; i += 256) FL[i] = fsrc[i];
  }
  const float* src = xsT + (size_t)series * TT;
  for (int i = tid; i < TT; i += 256) D[i] = make_float2(src[i], 0.f);
  __syncthreads();

  #pragma unroll
  for (int lh = 9; lh >= 1; lh -= 2) {
    const int h = 1 << lh;
    const int tstr = 512 >> lh;
    #pragma unroll
    for (int w = 0; w < 2; ++w) {
      const int u = tid + (w << 8);
      const int j = u & (h - 1);
      const int p = ((u >> lh) << (lh + 2)) + j;
      float2 x0 = D[p], x1 = D[p + h], x2 = D[p + 2 * h], x3 = D[p + 3 * h];
      float2 W  = TW[j * tstr];
      float2 W2 = TW[2 * j * tstr];
      float2 W3 = cmul(W, W2);
      float2 s02 = make_float2(x0.x + x2.x, x0.y + x2.y);
      float2 d02 = make_float2(x0.x - x2.x, x0.y - x2.y);
      float2 s13 = make_float2(x1.x + x3.x, x1.y + x3.y);
      float2 d13 = make_float2(x1.x - x3.x, x1.y - x3.y);
      D[p]         = make_float2(s02.x + s13.x, s02.y + s13.y);
      D[p + h]     = cmul(make_float2(s02.x - s13.x, s02.y - s13.y), W2);
      D[p + 2 * h] = cmul(make_float2(d02.x + d13.y, d02.y - d13.x), W);
      D[p + 3 * h] = cmul(make_float2(d02.x - d13.y, d02.y + d13.x), W3);
    }
    __syncthreads();
  }
  #pragma unroll
  for (int w = 0; w < 4; ++w) {
    const int u = tid + (w << 8);
    const int p = u * 2;
    float2 a = D[p], b = D[p + 1];
    D[p]     = make_float2(a.x + b.x, a.y + b.y);
    D[p + 1] = make_float2(a.x - b.x, a.y - b.y);
  }
  __syncthreads();

  for (int p = tid; p < TT; p += 256) {
    const int k = (int)(__brev((unsigned)p) >> 21);
    float2 f;
    if (k <= 1024) f = FL[k];
    else { f = FL[2048 - k]; f.y = -f.y; }
    float2 Xv = D[p];
    float pr = Xv.x * f.x - Xv.y * f.y;
    float pi = Xv.x * f.y + Xv.y * f.x;
    if (k == 0 || k == 1024) pi = 0.f;
    D[p] = make_float2(pr, pi);
  }
  __syncthreads();

  #pragma unroll
  for (int w = 0; w < 4; ++w) {
    const int u = tid + (w << 8);
    const int p = u * 2;
    float2 a = D[p], b = D[p + 1];
    D[p]     = make_float2(a.x + b.x, a.y + b.y);
    D[p + 1] = make_float2(a.x - b.x, a.y - b.y);
  }
  __syncthreads();
  #pragma unroll
  for (int lh = 1; lh <= 9; lh += 2) {
    const int h = 1 << lh;
    const int tstr = 512 >> lh;
    #pragma unroll
    for (int w = 0; w < 2; ++w) {
      const int u = tid + (w << 8);
      const int j = u & (h - 1);
      const int p = ((u >> lh) << (lh + 2)) + j;
      float2 z0 = D[p], z1 = D[p + h], z2 = D[p + 2 * h], z3 = D[p + 3 * h];
      float2 W  = TW[j * tstr];
      float2 W2 = TW[2 * j * tstr];
      float2 cW  = make_float2(W.x, -W.y);
      float2 cW2 = make_float2(W2.x, -W2.y);
      float2 icW = make_float2(-cW.y, cW.x);
      float2 t1 = cmul(z1, cW2);
      float2 y0 = make_float2(z0.x + t1.x, z0.y + t1.y);
      float2 y1 = make_float2(z0.x - t1.x, z0.y - t1.y);
      float2 t3 = cmul(z3, cW2);
      float2 y2 = make_float2(z2.x + t3.x, z2.y + t3.y);
      float2 y3 = make_float2(z2.x - t3.x, z2.y - t3.y);
      float2 u2 = cmul(y2, cW);
      float2 u3 = cmul(y3, icW);
      D[p]         = make_float2(y0.x + u2.x, y0.y + u2.y);
      D[p + 2 * h] = make_float2(y0.x - u2.x, y0.y - u2.y);
      D[p + h]     = make_float2(y1.x + u3.x, y1.y + u3.y);
      D[p + 3 * h] = make_float2(y1.x - u3.x, y1.y - u3.y);
    }
    __syncthreads();
  }

  const float inv = (1.0f / 2048.0f);
  const size_t obase = (size_t)bb * (TT * NN) + n;
  for (int t2 = tid; t2 < TT; t2 += 256) {
    xfreq[obase + (size_t)t2 * NN] = D[t2].x * inv;
  }
}

// ---------------------------------------------------------------------------
// Kernel 5: gate MLP via MFMA. 128 elements/block, 256 thr (4 waves).
// L1 acts -> bf16 A_lds[128][72]; W2^T bf16 in Wt_lds[64][72];
// C = A x W2 via 16 x mfma_f32_16x16x32_bf16 per wave (rows w*32..+31);
// epilogue: gelu(C+gb2) dot w3d row-reduced via shfl_xor -> sigmoid -> outputs.
// Rounds 4-7: every f32-VALU formulation of the 64-acc working set was
// demoted to scratch (546-620us); MFMA accumulators (f32x4 ext vectors)
// take the verified GEMM codegen path instead.
// ---------------------------------------------------------------------------
__global__ __launch_bounds__(256) void mlp_kernel(
    const float* __restrict__ xin, const float* __restrict__ mask, const int* __restrict__ rate_id,
    const float* __restrict__ rate_table,
    const float* __restrict__ gw1, const float* __restrict__ gb1,
    const float* __restrict__ gw2, const float* __restrict__ gb2,
    const float* __restrict__ gw3, const float* __restrict__ gb3,
    float* __restrict__ out)
{
  __shared__ uint16_t A_lds[128 * 72];
  __shared__ uint16_t Wt_lds[64 * 72];
  __shared__ __align__(16) float s_l1[512];     // [k][8]: slots 0..5 = gw1[c][k]
  __shared__ float s_b1rT[512];                 // [k][8]: per-rate L1 bias
  __shared__ float s_w3d[64], s_gb2[64];
  __shared__ float s_seed[128], s_gcn[128], s_freq[128], s_mask[128], s_xin[128];
  __shared__ float s_d[128];
  __shared__ int s_rid[64];
  const int tid = threadIdx.x;
  const size_t blk_base = (size_t)blockIdx.x * 128;

  // ---- stage weights + features ----
  for (int i = tid; i < 4096; i += 256) {
    int h = i >> 6, k = i & 63;
    Wt_lds[h * 72 + k] = f2bf(gw2[k * 64 + h]);   // Wt[h][k] = W2[k][h]
  }
  for (int i = tid; i < 512; i += 256) {
    int k = i >> 3, c = i & 7;
    s_l1[i] = (c < 6) ? gw1[c * 64 + k] : 0.f;
  }
  for (int i = tid; i < 512; i += 256) {
    int k = i >> 3, r = i & 7;
    float acc = gb1[k];
    #pragma unroll
    for (int e = 0; e < 16; ++e) acc += rate_table[r * 16 + e] * gw1[(6 + e) * 64 + k];
    s_b1rT[i] = acc;
  }
  if (tid < 64) {
    s_w3d[tid] = gw3[tid * 2] - gw3[tid * 2 + 1];
    s_gb2[tid] = gb2[tid];
    s_rid[tid] = rate_id[tid];
  }
  if (tid < 128) {
    size_t g = blk_base + tid;
    s_seed[tid] = out[g];
    s_gcn[tid]  = out[S_ELEMS + g];
    s_freq[tid] = out[2 * S_ELEMS + g];
  } else {
    int e = tid - 128;
    size_t g = blk_base + e;
    s_mask[e] = mask[g];
    s_xin[e]  = xin[g];
  }
  __syncthreads();

  // ---- L1: 32 activations per thread -> bf16 A_lds ----
  {
    const int e = tid & 127, half = tid >> 7;
    const float f0 = s_seed[e], f1 = s_mask[e], f2 = s_gcn[e], f3 = s_freq[e];
    const float f4 = f2 - f0, f5 = f3 - f0;
    const int rid = s_rid[e & 63];
    const float4* l1v = (const float4*)s_l1;
    #pragma unroll
    for (int i = 0; i < 16; ++i) {
      const int k0 = half * 32 + 2 * i;
      float4 wA0 = l1v[k0 * 2],       wB0 = l1v[k0 * 2 + 1];
      float4 wA1 = l1v[k0 * 2 + 2],   wB1 = l1v[k0 * 2 + 3];
      float a0 = s_b1rT[k0 * 8 + rid]
               + wA0.x * f0 + wA0.y * f1 + wA0.z * f2 + wA0.w * f3 + wB0.x * f4 + wB0.y * f5;
      float a1 = s_b1rT[(k0 + 1) * 8 + rid]
               + wA1.x * f0 + wA1.y * f1 + wA1.z * f2 + wA1.w * f3 + wB1.x * f4 + wB1.y * f5;
      uint32_t pk = (uint32_t)f2bf(gelu_f(a0)) | ((uint32_t)f2bf(gelu_f(a1)) << 16);
      *(uint32_t*)&A_lds[e * 72 + k0] = pk;
    }
  }
  __syncthreads();

  // ---- MFMA: per wave rows [wv*32, wv*32+32) x all 64 cols ----
  const int lane = tid & 63, wv = tid >> 6;
  const int r16 = lane & 15, g4 = lane >> 4;
  {
    const uint16_t* Ar0 = &A_lds[(wv * 32 +      r16) * 72 + g4 * 8];
    const uint16_t* Ar1 = &A_lds[(wv * 32 + 16 + r16) * 72 + g4 * 8];
    const uint16_t* Wr  = &Wt_lds[r16 * 72 + g4 * 8];

    f32x4 acc00 = {0.f,0.f,0.f,0.f}, acc01 = {0.f,0.f,0.f,0.f};
    f32x4 acc02 = {0.f,0.f,0.f,0.f}, acc03 = {0.f,0.f,0.f,0.f};
    f32x4 acc10 = {0.f,0.f,0.f,0.f}, acc11 = {0.f,0.f,0.f,0.f};
    f32x4 acc12 = {0.f,0.f,0.f,0.f}, acc13 = {0.f,0.f,0.f,0.f};

    #pragma unroll
    for (int kk = 0; kk < 2; ++kk) {
      const int ko = kk * 32;
      bf16x8 a0 = *(const bf16x8*)(Ar0 + ko);
      bf16x8 a1 = *(const bf16x8*)(Ar1 + ko);
      bf16x8 b0 = *(const bf16x8*)(Wr + ko);
      bf16x8 b1 = *(const bf16x8*)(Wr + 16 * 72 + ko);
      bf16x8 b2 = *(const bf16x8*)(Wr + 32 * 72 + ko);
      bf16x8 b3 = *(const bf16x8*)(Wr + 48 * 72 + ko);
      acc00 = __builtin_amdgcn_mfma_f32_16x16x32_bf16(a0, b0, acc00, 0, 0, 0);
      acc01 = __builtin_amdgcn_mfma_f32_16x16x32_bf16(a0, b1, acc01, 0, 0, 0);
      acc02 = __builtin_amdgcn_mfma_f32_16x16x32_bf16(a0, b2, acc02, 0, 0, 0);
      acc03 = __builtin_amdgcn_mfma_f32_16x16x32_bf16(a0, b3, acc03, 0, 0, 0);
      acc10 = __builtin_amdgcn_mfma_f32_16x16x32_bf16(a1, b0, acc10, 0, 0, 0);
      acc11 = __builtin_amdgcn_mfma_f32_16x16x32_bf16(a1, b1, acc11, 0, 0, 0);
      acc12 = __builtin_amdgcn_mfma_f32_16x16x32_bf16(a1, b2, acc12, 0, 0, 0);
      acc13 = __builtin_amdgcn_mfma_f32_16x16x32_bf16(a1, b3, acc13, 0, 0, 0);
    }

    // ---- epilogue: d(row) = sum_h gelu(C+gb2)[row][h] * w3d[h] ----
    const float gA = s_gb2[r16],      gB = s_gb2[16 + r16];
    const float gC = s_gb2[32 + r16], gD = s_gb2[48 + r16];
    const float wA = s_w3d[r16],      wB = s_w3d[16 + r16];
    const float wC = s_w3d[32 + r16], wD = s_w3d[48 + r16];

#define ROWRED(tr, v, A0, A1, A2, A3) { \
    float p = gelu_f(A0[v] + gA) * wA + gelu_f(A1[v] + gB) * wB \
            + gelu_f(A2[v] + gC) * wC + gelu_f(A3[v] + gD) * wD; \
    p += __shfl_xor(p, 1, 64); p += __shfl_xor(p, 2, 64); \
    p += __shfl_xor(p, 4, 64); p += __shfl_xor(p, 8, 64); \
    if (r16 == 0) s_d[wv * 32 + tr * 16 + g4 * 4 + v] = p; }

    ROWRED(0, 0, acc00, acc01, acc02, acc03)
    ROWRED(0, 1, acc00, acc01, acc02, acc03)
    ROWRED(0, 2, acc00, acc01, acc02, acc03)
    ROWRED(0, 3, acc00, acc01, acc02, acc03)
    ROWRED(1, 0, acc10, acc11, acc12, acc13)
    ROWRED(1, 1, acc10, acc11, acc12, acc13)
    ROWRED(1, 2, acc10, acc11, acc12, acc13)
    ROWRED(1, 3, acc10, acc11, acc12, acc13)
#undef ROWRED
  }
  __syncthreads();

  // ---- final: sigmoid + expert combine, coalesced writes ----
  if (tid < 128) {
    const size_t g = blk_base + tid;
    float d = s_d[tid] + gb3[0] - gb3[1];
    float w0 = __fdividef(1.0f, 1.0f + __expf(-d));
    float w1g = 1.0f - w0;
    float ximp = w0 * s_gcn[tid] + w1g * s_freq[tid];
    out[3 * S_ELEMS + g] = ximp;
    out[4 * S_ELEMS + g] = (s_mask[tid] != 0.0f) ? ximp : s_xin[tid];
    ((float2*)(out + 5 * S_ELEMS))[g] = make_float2(w0, w1g);
  }
}

// ---------------------------------------------------------------------------
extern "C" void kernel_launch(void* const* d_in, const int* in_sizes, int n_in,
                              void* d_out, int out_size, void* d_ws, size_t ws_size,
                              hipStream_t stream) {
  (void)in_sizes; (void)n_in; (void)out_size; (void)d_ws; (void)ws_size;
  const float* x_input    = (const float*)d_in[0];
  const float* mask       = (const float*)d_in[1];
  const int*   rate_id    = (const int*)d_in[2];
  const float* node_emb   = (const float*)d_in[3];
  const float* gcn_w1     = (const float*)d_in[4];
  const float* gcn_b1     = (const float*)d_in[5];
  const float* gcn_w2     = (const float*)d_in[6];
  const float* gcn_b2     = (const float*)d_in[7];
  const float* freq_re    = (const float*)d_in[8];
  const float* freq_im    = (const float*)d_in[9];
  const float* rate_table = (const float*)d_in[10];
  const float* gw1        = (const float*)d_in[11];
  const float* gb1        = (const float*)d_in[12];
  const float* gw2        = (const float*)d_in[13];
  const float* gb2        = (const float*)d_in[14];
  const float* gw3        = (const float*)d_in[15];
  const float* gb3        = (const float*)d_in[16];
  float* out = (float*)d_out;

  float* out0 = out;                 // x_seed
  float* out1 = out + S_ELEMS;       // x_gcn
  float* out2 = out + 2 * S_ELEMS;   // x_freq
  float* out4 = out + 4 * S_ELEMS;   // scratch (seed^T) -> x_complete (mlp)
  float* out6 = out + 7 * S_ELEMS;   // adjacency
  float2* filtT = (float2*)(out + 5 * S_ELEMS);  // scratch -> gate weights (mlp)

  fill_kernel<<<256, 256, 0, stream>>>(x_input, mask, out0, out4);
  adj_prep_kernel<<<6, 256, 0, stream>>>(node_emb, freq_re, freq_im, out6, filtT);
  gcn_kernel<<<1024, 256, 0, stream>>>(out0, out6, gcn_w1, gcn_b1, gcn_w2, gcn_b2, out1);
  fft_kernel<<<1024, 256, 0, stream>>>(out4, filtT, out2);
  mlp_kernel<<<16384, 256, 0, stream>>>(x_input, mask, rate_id, rate_table,
                                        gw1, gb1, gw2, gb2, gw3, gb3, out);
}

// Round 10
// 470.429 us; speedup vs baseline: 1.5514x; 1.0642x over previous
//
#include <hip/hip_runtime.h>
#include <cstdint>

#define S_ELEMS 2097152ull   // B*T*N = 16*2048*64
#define TT 2048
#define NN 64

typedef __attribute__((ext_vector_type(8))) short bf16x8;
typedef __attribute__((ext_vector_type(4))) float f32x4;

__device__ __forceinline__ float gelu_f(float x) {
  float x2 = x * x;
  float z = -1.5957691216057308f * x * (1.0f + 0.044715f * x2);
  return __fdividef(x, 1.0f + __expf(z));
}

__device__ __forceinline__ float2 cmul(float2 a, float2 b) {
  return make_float2(a.x * b.x - a.y * b.y, a.x * b.y + a.y * b.x);
}

__device__ __forceinline__ uint16_t f2bf(float x) {   // RNE float->bf16 bits
  uint32_t u = __float_as_uint(x);
  return (uint16_t)((u + 0x7FFFu + ((u >> 16) & 1u)) >> 16);
}

// ---------------------------------------------------------------------------
// Kernel 1: warm_start_fill. (unchanged)
// ---------------------------------------------------------------------------
__global__ __launch_bounds__(256) void fill_kernel(
    const float* __restrict__ x, const float* __restrict__ mask,
    float* __restrict__ seed_out, float* __restrict__ xsT)
{
  __shared__ float s_last[64][4], s_vfirst[64][4];
  __shared__ int   s_has[64][4], s_fidx[64][4];
  __shared__ float s_cl[64][4], s_bv[64][4];
  __shared__ int   s_ch[64][4], s_bh[64][4];
  __shared__ int   s_fg[4];

  const int tid = threadIdx.x;
  const int s4 = tid & 3, c = tid >> 2;
  const int b = blockIdx.x >> 4;
  const int n = ((blockIdx.x & 15) << 2) + s4;
  const size_t base = (size_t)b * (TT * NN) + n;
  const int t0 = c << 5;

  float ff[32];
  float last = 0.f; int has = 0; int fidx = TT; float vfirst = 0.f;
  #pragma unroll
  for (int i = 0; i < 32; ++i) {
    size_t off = base + (size_t)(t0 + i) * NN;
    float v = x[off];
    float m = mask[off];
    bool obs = (m == 0.0f);
    if (obs) { last = v; if (!has) { has = 1; fidx = t0 + i; vfirst = v; } }
    ff[i] = obs ? v : last;
  }
  s_last[c][s4] = last; s_has[c][s4] = has;
  s_vfirst[c][s4] = vfirst; s_fidx[c][s4] = fidx;
  __syncthreads();

  if (tid < 4) {
    float cl = 0.f; int ch = 0; int fg = TT;
    for (int cc = 0; cc < 64; ++cc) {
      s_cl[cc][tid] = cl; s_ch[cc][tid] = ch;
      if (s_has[cc][tid]) {
        cl = s_last[cc][tid]; ch = 1;
        if (fg == TT) fg = s_fidx[cc][tid];
      }
    }
    s_fg[tid] = fg;
    float bv = 0.f; int bh = 0;
    for (int cc = 63; cc >= 0; --cc) {
      s_bv[cc][tid] = bv; s_bh[cc][tid] = bh;
      if (s_has[cc][tid]) { bv = s_vfirst[cc][tid]; bh = 1; }
    }
  }
  __syncthreads();

  const float cl  = s_cl[c][s4]; const int ch  = s_ch[c][s4];
  const float bcv = s_bv[c][s4]; const int bch = s_bh[c][s4];
  const int firstg = s_fg[s4];
  const float pre = ch ? cl : 0.f;
  const int floc = fidx - t0;
  const size_t tbase = ((size_t)b * NN + n) * TT;

  float lastb = 0.f; int hasb = 0;
  float xb0, xb1, xb2, xb3;
  #pragma unroll
  for (int i = 31; i >= 0; --i) {
    int t = t0 + i;
    size_t off = base + (size_t)t * NN;
    float v = x[off];
    float m = mask[off];
    bool obs = (m == 0.0f);
    if (obs) { lastb = v; hasb = 1; }
    float bf = hasb ? lastb : bcv;
    int bav = hasb | bch;
    float ffv = (i < floc) ? pre : ff[i];
    int fav = (t >= firstg) ? 1 : 0;
    float sv;
    if (obs) sv = v;
    else if (fav && bav) sv = 0.5f * (ffv + bf);
    else if (fav) sv = ffv;
    else if (bav) sv = bf;
    else sv = 0.f;
    seed_out[off] = sv;
    if ((i & 3) == 3) xb3 = sv;
    else if ((i & 3) == 2) xb2 = sv;
    else if ((i & 3) == 1) xb1 = sv;
    else {
      xb0 = sv;
      *(float4*)(xsT + tbase + t) = make_float4(xb0, xb1, xb2, xb3);
    }
  }
}

// ---------------------------------------------------------------------------
// Kernel 2: adjacency + filter transpose. (unchanged)
// ---------------------------------------------------------------------------
__global__ __launch_bounds__(256) void adj_prep_kernel(
    const float* __restrict__ node_emb,
    const float* __restrict__ fre, const float* __restrict__ fim,
    float* __restrict__ adj, float2* __restrict__ filtT)
{
  const int tid = threadIdx.x;
  if (blockIdx.x == 0) {
    __shared__ float E[64 * 32];
    for (int i = tid; i < 2048; i += 256) E[i] = node_emb[i];
    __syncthreads();
    if (tid < 64) {
      float er[32];
      #pragma unroll
      for (int k = 0; k < 32; ++k) er[k] = E[tid * 32 + k];
      float sc[64];
      float mx = -1e30f;
      #pragma unroll
      for (int j = 0; j < 64; ++j) {
        float acc = 0.f;
        #pragma unroll
        for (int k = 0; k < 32; ++k) acc += er[k] * E[j * 32 + k];
        acc = fmaxf(acc, 0.f);
        sc[j] = acc;
        mx = fmaxf(mx, acc);
      }
      float sum = 0.f;
      #pragma unroll
      for (int j = 0; j < 64; ++j) { float e = __expf(sc[j] - mx); sc[j] = e; sum += e; }
      float inv = __fdividef(1.f, sum);
      #pragma unroll
      for (int j = 0; j < 64; ++j) adj[tid * 64 + j] = sc[j] * inv;
    }
  } else {
    for (int idx = (blockIdx.x - 1) * 256 + tid; idx < 1025 * 64; idx += 5 * 256) {
      int k = idx >> 6, nn = idx & 63;
      filtT[(size_t)nn * 1025 + k] = make_float2(fre[idx], fim[idx]);
    }
  }
}

// ---------------------------------------------------------------------------
// Kernel 3: x_gcn, 32 rows/block. (unchanged)
// ---------------------------------------------------------------------------
__global__ __launch_bounds__(256) void gcn_kernel(
    const float* __restrict__ seed, const float* __restrict__ adj,
    const float* __restrict__ w1, const float* __restrict__ b1,
    const float* __restrict__ w2, const float* __restrict__ b2p,
    float* __restrict__ xgcn)
{
  __shared__ float At[64 * 65];
  __shared__ float su[4][64];
  __shared__ float sw1[32], sb1[32], sw2[32];
  const int tid = threadIdx.x;
  for (int i = tid; i < 4096; i += 256) {
    int nn = i >> 6, m = i & 63;
    At[m * 65 + nn] = adj[i];
  }
  if (tid < 32) { sw1[tid] = w1[tid]; sb1[tid] = b1[tid]; sw2[tid] = w2[tid]; }
  const float b2 = b2p[0];
  const int r = tid >> 6, n = tid & 63;
  const size_t row0 = (size_t)blockIdx.x * 32;

  for (int it = 0; it < 8; ++it) {
    __syncthreads();
    size_t row = row0 + it * 4 + r;
    float xv = seed[row * 64 + n];
    float u = 0.f;
    #pragma unroll
    for (int h = 0; h < 32; ++h) u += sw2[h] * gelu_f(xv * sw1[h] + sb1[h]);
    su[r][n] = u;
    __syncthreads();
    float acc = b2;
    #pragma unroll 16
    for (int m = 0; m < 64; ++m) acc += At[m * 65 + n] * su[r][m];
    xgcn[row * 64 + n] = acc;
  }
}

// ---------------------------------------------------------------------------
// Kernel 4: FFT filter, radix-4. (unchanged)
// ---------------------------------------------------------------------------
__global__ __launch_bounds__(256) void fft_kernel(
    const float* __restrict__ xsT, const float2* __restrict__ filtT,
    float* __restrict__ xfreq)
{
  __shared__ float2 D[2048];
  __shared__ float2 TW[1024];
  __shared__ float2 FL[1025];
  const int tid = threadIdx.x;
  const int series = blockIdx.x;
  const int bb = series >> 6, n = series & 63;

  for (int m = tid; m < 1024; m += 256) {
    float s, c;
    __sincosf(-3.0679615757712823e-3f * (float)m, &s, &c);  // -2*pi*m/2048
    TW[m] = make_float2(c, s);
  }
  {
    const float2* fsrc = filtT + (size_t)n * 1025;
    for (int i = tid; i < 1025; i += 256) FL[i] = fsrc[i];
  }
  const float* src = xsT + (size_t)series * TT;
  for (int i = tid; i < TT; i += 256) D[i] = make_float2(src[i], 0.f);
  __syncthreads();

  #pragma unroll
  for (int lh = 9; lh >= 1; lh -= 2) {
    const int h = 1 << lh;
    const int tstr = 512 >> lh;
    #pragma unroll
    for (int w = 0; w < 2; ++w) {
      const int u = tid + (w << 8);
      const int j = u & (h - 1);
      const int p = ((u >> lh) << (lh + 2)) + j;
      float2 x0 = D[p], x1 = D[p + h], x2 = D[p + 2 * h], x3 = D[p + 3 * h];
      float2 W  = TW[j * tstr];
      float2 W2 = TW[2 * j * tstr];
      float2 W3 = cmul(W, W2);
      float2 s02 = make_float2(x0.x + x2.x, x0.y + x2.y);
      float2 d02 = make_float2(x0.x - x2.x, x0.y - x2.y);
      float2 s13 = make_float2(x1.x + x3.x, x1.y + x3.y);
      float2 d13 = make_float2(x1.x - x3.x, x1.y - x3.y);
      D[p]         = make_float2(s02.x + s13.x, s02.y + s13.y);
      D[p + h]     = cmul(make_float2(s02.x - s13.x, s02.y - s13.y), W2);
      D[p + 2 * h] = cmul(make_float2(d02.x + d13.y, d02.y - d13.x), W);
      D[p + 3 * h] = cmul(make_float2(d02.x - d13.y, d02.y + d13.x), W3);
    }
    __syncthreads();
  }
  #pragma unroll
  for (int w = 0; w < 4; ++w) {
    const int u = tid + (w << 8);
    const int p = u * 2;
    float2 a = D[p], b = D[p + 1];
    D[p]     = make_float2(a.x + b.x, a.y + b.y);
    D[p + 1] = make_float2(a.x - b.x, a.y - b.y);
  }
  __syncthreads();

  for (int p = tid; p < TT; p += 256) {
    const int k = (int)(__brev((unsigned)p) >> 21);
    float2 f;
    if (k <= 1024) f = FL[k];
    else { f = FL[2048 - k]; f.y = -f.y; }
    float2 Xv = D[p];
    float pr = Xv.x * f.x - Xv.y * f.y;
    float pi = Xv.x * f.y + Xv.y * f.x;
    if (k == 0 || k == 1024) pi = 0.f;
    D[p] = make_float2(pr, pi);
  }
  __syncthreads();

  #pragma unroll
  for (int w = 0; w < 4; ++w) {
    const int u = tid + (w << 8);
    const int p = u * 2;
    float2 a = D[p], b = D[p + 1];
    D[p]     = make_float2(a.x + b.x, a.y + b.y);
    D[p + 1] = make_float2(a.x - b.x, a.y - b.y);
  }
  __syncthreads();
  #pragma unroll
  for (int lh = 1; lh <= 9; lh += 2) {
    const int h = 1 << lh;
    const int tstr = 512 >> lh;
    #pragma unroll
    for (int w = 0; w < 2; ++w) {
      const int u = tid + (w << 8);
      const int j = u & (h - 1);
      const int p = ((u >> lh) << (lh + 2)) + j;
      float2 z0 = D[p], z1 = D[p + h], z2 = D[p + 2 * h], z3 = D[p + 3 * h];
      float2 W  = TW[j * tstr];
      float2 W2 = TW[2 * j * tstr];
      float2 cW  = make_float2(W.x, -W.y);
      float2 cW2 = make_float2(W2.x, -W2.y);
      float2 icW = make_float2(-cW.y, cW.x);
      float2 t1 = cmul(z1, cW2);
      float2 y0 = make_float2(z0.x + t1.x, z0.y + t1.y);
      float2 y1 = make_float2(z0.x - t1.x, z0.y - t1.y);
      float2 t3 = cmul(z3, cW2);
      float2 y2 = make_float2(z2.x + t3.x, z2.y + t3.y);
      float2 y3 = make_float2(z2.x - t3.x, z2.y - t3.y);
      float2 u2 = cmul(y2, cW);
      float2 u3 = cmul(y3, icW);
      D[p]         = make_float2(y0.x + u2.x, y0.y + u2.y);
      D[p + 2 * h] = make_float2(y0.x - u2.x, y0.y - u2.y);
      D[p + h]     = make_float2(y1.x + u3.x, y1.y + u3.y);
      D[p + 3 * h] = make_float2(y1.x - u3.x, y1.y - u3.y);
    }
    __syncthreads();
  }

  const float inv = (1.0f / 2048.0f);
  const size_t obase = (size_t)bb * (TT * NN) + n;
  for (int t2 = tid; t2 < TT; t2 += 256) {
    xfreq[obase + (size_t)t2 * NN] = D[t2].x * inv;
  }
}

// ---------------------------------------------------------------------------
// Kernel 5: gate MLP, MFMA + fragment-direct L1 + chunked weight reuse.
// 2048 blocks x 256 thr, 8 chunks of 128 elements per block.
// Round-9 lessons: staging repeated 16384x, A_lds roundtrip (8-way write
// conflicts), uncoalesced gw2 reads -> 303us at MfmaUtil 2.45%. This version:
// weights staged once/block (8x amortized, coalesced gw2), acts computed
// directly into MFMA A-fragments (A_lds deleted), b1rT stride-9 padding.
// ---------------------------------------------------------------------------
__global__ __launch_bounds__(256, 3) void mlp_kernel(
    const float* __restrict__ xin, const float* __restrict__ mask, const int* __restrict__ rate_id,
    const float* __restrict__ rate_table,
    const float* __restrict__ gw1, const float* __restrict__ gb1,
    const float* __restrict__ gw2, const float* __restrict__ gb2,
    const float* __restrict__ gw3, const float* __restrict__ gb3,
    float* __restrict__ out)
{
  __shared__ uint16_t Wt_lds[64 * 72];          // Wt[h][k] = W2[k][h], bf16
  __shared__ __align__(16) float s_l1[512];     // [k][8]: slots 0..5 = gw1[c][k]
  __shared__ float s_b1rT[64 * 9];              // [k][9]: per-rate L1 bias, pad 9
  __shared__ float s_w3d[64], s_gb2[64];
  __shared__ float s_feat[5][128];              // seed,gcn,freq,mask,xin
  __shared__ float s_d[128];
  __shared__ int s_rid[64];
  const int tid = threadIdx.x;

  // ---- one-time staging (coalesced gw2 read; LDS scatter write) ----
  for (int i = tid; i < 4096; i += 256) {
    int k = i >> 6, h = i & 63;
    Wt_lds[h * 72 + k] = f2bf(gw2[i]);
  }
  for (int i = tid; i < 512; i += 256) {
    int k = i >> 3, c = i & 7;
    s_l1[i] = (c < 6) ? gw1[c * 64 + k] : 0.f;
  }
  for (int i = tid; i < 512; i += 256) {
    int k = i >> 3, r = i & 7;
    float acc = gb1[k];
    #pragma unroll
    for (int e = 0; e < 16; ++e) acc += rate_table[r * 16 + e] * gw1[(6 + e) * 64 + k];
    s_b1rT[k * 9 + r] = acc;
  }
  if (tid < 64) {
    s_w3d[tid] = gw3[tid * 2] - gw3[tid * 2 + 1];
    s_gb2[tid] = gb2[tid];
    s_rid[tid] = rate_id[tid];
  }
  const float dbias = gb3[0] - gb3[1];

  const int lane = tid & 63, wv = tid >> 6;
  const int r16 = lane & 15, g4 = lane >> 4;
  const float4* l1v = (const float4*)s_l1;

  for (int ch = 0; ch < 8; ++ch) {
    const size_t blk_base = ((size_t)blockIdx.x * 8 + ch) * 128;
    __syncthreads();   // weights ready (ch=0) / prev chunk fully consumed (ch>0)
    if (tid < 128) {
      size_t g = blk_base + tid;
      s_feat[0][tid] = out[g];
      s_feat[1][tid] = out[S_ELEMS + g];
      s_feat[2][tid] = out[2 * S_ELEMS + g];
    } else {
      int e = tid - 128;
      size_t g = blk_base + e;
      s_feat[3][e] = mask[g];
      s_feat[4][e] = xin[g];
    }
    __syncthreads();

    // A-matrix rows owned by this lane: e0 (row-group 0), e1 (row-group 1)
    const int e0 = wv * 32 + r16, e1 = e0 + 16;
    const float s0 = s_feat[0][e0], m0 = s_feat[3][e0];
    const float g0 = s_feat[1][e0], q0 = s_feat[2][e0];
    const float s1 = s_feat[0][e1], m1 = s_feat[3][e1];
    const float g1 = s_feat[1][e1], q1 = s_feat[2][e1];
    const float d0 = g0 - s0, p0 = q0 - s0;
    const float d1 = g1 - s1, p1 = q1 - s1;
    const int rid0 = s_rid[e0 & 63];
    const int rid1 = s_rid[e1 & 63];

    f32x4 acc00 = {0.f,0.f,0.f,0.f}, acc01 = {0.f,0.f,0.f,0.f};
    f32x4 acc02 = {0.f,0.f,0.f,0.f}, acc03 = {0.f,0.f,0.f,0.f};
    f32x4 acc10 = {0.f,0.f,0.f,0.f}, acc11 = {0.f,0.f,0.f,0.f};
    f32x4 acc12 = {0.f,0.f,0.f,0.f}, acc13 = {0.f,0.f,0.f,0.f};

    #pragma unroll
    for (int ks = 0; ks < 2; ++ks) {
      // acts straight into A-fragments (k = ks*32 + g4*8 + j)
      bf16x8 a0, a1;
      #pragma unroll
      for (int j = 0; j < 8; ++j) {
        const int k = ks * 32 + g4 * 8 + j;
        float4 wA = l1v[k * 2], wB = l1v[k * 2 + 1];
        float bb0 = s_b1rT[k * 9 + rid0];
        float bb1 = s_b1rT[k * 9 + rid1];
        float v0 = bb0 + wA.x * s0 + wA.y * m0 + wA.z * g0 + wA.w * q0 + wB.x * d0 + wB.y * p0;
        float v1 = bb1 + wA.x * s1 + wA.y * m1 + wA.z * g1 + wA.w * q1 + wB.x * d1 + wB.y * p1;
        a0[j] = (short)f2bf(gelu_f(v0));
        a1[j] = (short)f2bf(gelu_f(v1));
      }
      const uint16_t* Wr = &Wt_lds[r16 * 72 + ks * 32 + g4 * 8];
      bf16x8 b0 = *(const bf16x8*)(Wr);
      bf16x8 b1 = *(const bf16x8*)(Wr + 16 * 72);
      bf16x8 b2 = *(const bf16x8*)(Wr + 32 * 72);
      bf16x8 b3 = *(const bf16x8*)(Wr + 48 * 72);
      acc00 = __builtin_amdgcn_mfma_f32_16x16x32_bf16(a0, b0, acc00, 0, 0, 0);
      acc01 = __builtin_amdgcn_mfma_f32_16x16x32_bf16(a0, b1, acc01, 0, 0, 0);
      acc02 = __builtin_amdgcn_mfma_f32_16x16x32_bf16(a0, b2, acc02, 0, 0, 0);
      acc03 = __builtin_amdgcn_mfma_f32_16x16x32_bf16(a0, b3, acc03, 0, 0, 0);
      acc10 = __builtin_amdgcn_mfma_f32_16x16x32_bf16(a1, b0, acc10, 0, 0, 0);
      acc11 = __builtin_amdgcn_mfma_f32_16x16x32_bf16(a1, b1, acc11, 0, 0, 0);
      acc12 = __builtin_amdgcn_mfma_f32_16x16x32_bf16(a1, b2, acc12, 0, 0, 0);
      acc13 = __builtin_amdgcn_mfma_f32_16x16x32_bf16(a1, b3, acc13, 0, 0, 0);
    }

    // epilogue: d(row) = sum_h gelu(C+gb2)[row][h] * w3d[h]; C col=lane&15,
    // row=(lane>>4)*4+reg (verified round 9 via absmax pass)
    {
      const float gA = s_gb2[r16],      gB = s_gb2[16 + r16];
      const float gC = s_gb2[32 + r16], gD = s_gb2[48 + r16];
      const float wA = s_w3d[r16],      wB = s_w3d[16 + r16];
      const float wC = s_w3d[32 + r16], wD = s_w3d[48 + r16];

#define ROWRED(tr, v, A0, A1, A2, A3) { \
      float p = gelu_f(A0[v] + gA) * wA + gelu_f(A1[v] + gB) * wB \
              + gelu_f(A2[v] + gC) * wC + gelu_f(A3[v] + gD) * wD; \
      p += __shfl_xor(p, 1, 64); p += __shfl_xor(p, 2, 64); \
      p += __shfl_xor(p, 4, 64); p += __shfl_xor(p, 8, 64); \
      if (r16 == 0) s_d[wv * 32 + tr * 16 + g4 * 4 + v] = p; }

      ROWRED(0, 0, acc00, acc01, acc02, acc03)
      ROWRED(0, 1, acc00, acc01, acc02, acc03)
      ROWRED(0, 2, acc00, acc01, acc02, acc03)
      ROWRED(0, 3, acc00, acc01, acc02, acc03)
      ROWRED(1, 0, acc10, acc11, acc12, acc13)
      ROWRED(1, 1, acc10, acc11, acc12, acc13)
      ROWRED(1, 2, acc10, acc11, acc12, acc13)
      ROWRED(1, 3, acc10, acc11, acc12, acc13)
#undef ROWRED
    }
    __syncthreads();

    if (tid < 128) {
      const size_t g = blk_base + tid;
      float d = s_d[tid] + dbias;
      float w0 = __fdividef(1.0f, 1.0f + __expf(-d));
      float w1g = 1.0f - w0;
      float ximp = w0 * s_feat[1][tid] + w1g * s_feat[2][tid];
      out[3 * S_ELEMS + g] = ximp;
      out[4 * S_ELEMS + g] = (s_feat[3][tid] != 0.0f) ? ximp : s_feat[4][tid];
      ((float2*)(out + 5 * S_ELEMS))[g] = make_float2(w0, w1g);
    }
  }
}

// ---------------------------------------------------------------------------
extern "C" void kernel_launch(void* const* d_in, const int* in_sizes, int n_in,
                              void* d_out, int out_size, void* d_ws, size_t ws_size,
                              hipStream_t stream) {
  (void)in_sizes; (void)n_in; (void)out_size; (void)d_ws; (void)ws_size;
  const float* x_input    = (const float*)d_in[0];
  const float* mask       = (const float*)d_in[1];
  const int*   rate_id    = (const int*)d_in[2];
  const float* node_emb   = (const float*)d_in[3];
  const float* gcn_w1     = (const float*)d_in[4];
  const float* gcn_b1     = (const float*)d_in[5];
  const float* gcn_w2     = (const float*)d_in[6];
  const float* gcn_b2     = (const float*)d_in[7];
  const float* freq_re    = (const float*)d_in[8];
  const float* freq_im    = (const float*)d_in[9];
  const float* rate_table = (const float*)d_in[10];
  const float* gw1        = (const float*)d_in[11];
  const float* gb1        = (const float*)d_in[12];
  const float* gw2        = (const float*)d_in[13];
  const float* gb2        = (const float*)d_in[14];
  const float* gw3        = (const float*)d_in[15];
  const float* gb3        = (const float*)d_in[16];
  float* out = (float*)d_out;

  float* out0 = out;                 // x_seed
  float* out1 = out + S_ELEMS;       // x_gcn
  float* out2 = out + 2 * S_ELEMS;   // x_freq
  float* out4 = out + 4 * S_ELEMS;   // scratch (seed^T) -> x_complete (mlp)
  float* out6 = out + 7 * S_ELEMS;   // adjacency
  float2* filtT = (float2*)(out + 5 * S_ELEMS);  // scratch -> gate weights (mlp)

  fill_kernel<<<256, 256, 0, stream>>>(x_input, mask, out0, out4);
  adj_prep_kernel<<<6, 256, 0, stream>>>(node_emb, freq_re, freq_im, out6, filtT);
  gcn_kernel<<<1024, 256, 0, stream>>>(out0, out6, gcn_w1, gcn_b1, gcn_w2, gcn_b2, out1);
  fft_kernel<<<1024, 256, 0, stream>>>(out4, filtT, out2);
  mlp_kernel<<<2048, 256, 0, stream>>>(x_input, mask, rate_id, rate_table,
                                       gw1, gb1, gw2, gb2, gw3, gb3, out);
}